// Round 11
// baseline (358.447 us; speedup 1.0000x reference)
//
#include <hip/hip_runtime.h>
#include <hip/hip_bf16.h>

#define HID 96
#define NGRAPHS 64
#define SENT 0xC3C3u   // 50115: sentinel row (zeroed) for CSR padding
#define NROWS 50116    // N + sentinel row

typedef __attribute__((ext_vector_type(8))) short short8;
typedef __attribute__((ext_vector_type(4))) float floatx4;
typedef __attribute__((ext_vector_type(8))) unsigned short ushort8v;

__device__ __forceinline__ float bf16_to_f32(unsigned short u) {
    unsigned int v = ((unsigned int)u) << 16;
    return __builtin_bit_cast(float, v);
}
__device__ __forceinline__ unsigned short f32_to_bf16(float f) {
    unsigned int u = __builtin_bit_cast(unsigned int, f);
    u += 0x7fff + ((u >> 16) & 1);  // RNE
    return (unsigned short)(u >> 16);
}

// One 8-edge batch of one row.
__device__ __forceinline__ void gather_batch(const unsigned short* __restrict__ h,
                                             const unsigned short* __restrict__ csr,
                                             int i, int fi, float& a0, float& a1) {
    ushort8v iv = *(const ushort8v*)(csr + i);
    ushort2 v0 = *(const ushort2*)(h + (size_t)iv[0] * HID + fi);
    ushort2 v1 = *(const ushort2*)(h + (size_t)iv[1] * HID + fi);
    ushort2 v2 = *(const ushort2*)(h + (size_t)iv[2] * HID + fi);
    ushort2 v3 = *(const ushort2*)(h + (size_t)iv[3] * HID + fi);
    ushort2 v4 = *(const ushort2*)(h + (size_t)iv[4] * HID + fi);
    ushort2 v5 = *(const ushort2*)(h + (size_t)iv[5] * HID + fi);
    ushort2 v6 = *(const ushort2*)(h + (size_t)iv[6] * HID + fi);
    ushort2 v7 = *(const ushort2*)(h + (size_t)iv[7] * HID + fi);
    a0 += bf16_to_f32(v0.x) + bf16_to_f32(v1.x) + bf16_to_f32(v2.x) +
          bf16_to_f32(v3.x) + bf16_to_f32(v4.x) + bf16_to_f32(v5.x) +
          bf16_to_f32(v6.x) + bf16_to_f32(v7.x);
    a1 += bf16_to_f32(v0.y) + bf16_to_f32(v1.y) + bf16_to_f32(v2.y) +
          bf16_to_f32(v3.y) + bf16_to_f32(v4.y) + bf16_to_f32(v5.y) +
          bf16_to_f32(v6.y) + bf16_to_f32(v7.y);
}

// Two rows gathered concurrently; 16+ loads in flight per wave.
__device__ __forceinline__ void gather2(const unsigned short* __restrict__ h,
                                        const unsigned short* __restrict__ csr,
                                        int i0, int e0, int i1, int e1, int fi,
                                        float& a00, float& a01, float& a10,
                                        float& a11) {
    while (i0 < e0 && i1 < e1) {
        ushort8v ca = *(const ushort8v*)(csr + i0);
        ushort8v cb = *(const ushort8v*)(csr + i1);
        i0 += 8;
        i1 += 8;
        ushort2 u0 = *(const ushort2*)(h + (size_t)ca[0] * HID + fi);
        ushort2 u1 = *(const ushort2*)(h + (size_t)ca[1] * HID + fi);
        ushort2 u2 = *(const ushort2*)(h + (size_t)ca[2] * HID + fi);
        ushort2 u3 = *(const ushort2*)(h + (size_t)ca[3] * HID + fi);
        ushort2 u4 = *(const ushort2*)(h + (size_t)ca[4] * HID + fi);
        ushort2 u5 = *(const ushort2*)(h + (size_t)ca[5] * HID + fi);
        ushort2 u6 = *(const ushort2*)(h + (size_t)ca[6] * HID + fi);
        ushort2 u7 = *(const ushort2*)(h + (size_t)ca[7] * HID + fi);
        ushort2 w0 = *(const ushort2*)(h + (size_t)cb[0] * HID + fi);
        ushort2 w1 = *(const ushort2*)(h + (size_t)cb[1] * HID + fi);
        ushort2 w2 = *(const ushort2*)(h + (size_t)cb[2] * HID + fi);
        ushort2 w3 = *(const ushort2*)(h + (size_t)cb[3] * HID + fi);
        ushort2 w4 = *(const ushort2*)(h + (size_t)cb[4] * HID + fi);
        ushort2 w5 = *(const ushort2*)(h + (size_t)cb[5] * HID + fi);
        ushort2 w6 = *(const ushort2*)(h + (size_t)cb[6] * HID + fi);
        ushort2 w7 = *(const ushort2*)(h + (size_t)cb[7] * HID + fi);
        a00 += bf16_to_f32(u0.x) + bf16_to_f32(u1.x) + bf16_to_f32(u2.x) +
               bf16_to_f32(u3.x) + bf16_to_f32(u4.x) + bf16_to_f32(u5.x) +
               bf16_to_f32(u6.x) + bf16_to_f32(u7.x);
        a01 += bf16_to_f32(u0.y) + bf16_to_f32(u1.y) + bf16_to_f32(u2.y) +
               bf16_to_f32(u3.y) + bf16_to_f32(u4.y) + bf16_to_f32(u5.y) +
               bf16_to_f32(u6.y) + bf16_to_f32(u7.y);
        a10 += bf16_to_f32(w0.x) + bf16_to_f32(w1.x) + bf16_to_f32(w2.x) +
               bf16_to_f32(w3.x) + bf16_to_f32(w4.x) + bf16_to_f32(w5.x) +
               bf16_to_f32(w6.x) + bf16_to_f32(w7.x);
        a11 += bf16_to_f32(w0.y) + bf16_to_f32(w1.y) + bf16_to_f32(w2.y) +
               bf16_to_f32(w3.y) + bf16_to_f32(w4.y) + bf16_to_f32(w5.y) +
               bf16_to_f32(w6.y) + bf16_to_f32(w7.y);
    }
    for (; i0 < e0; i0 += 8) gather_batch(h, csr, i0, fi, a00, a01);
    for (; i1 < e1; i1 += 8) gather_batch(h, csr, i1, fi, a10, a11);
}

// ------------------------------------------------------------------ init ----
// Replaces: memset(deg), memset(psum), zero_sentinel.
__global__ __launch_bounds__(256) void init_kernel(
    int* __restrict__ deg, float* __restrict__ psum,
    unsigned short* __restrict__ bufA, unsigned short* __restrict__ bufB, int N) {
    int i = blockIdx.x * 256 + threadIdx.x;
    if (i < N) deg[i] = 0;
    if (i < NGRAPHS * HID + NGRAPHS) psum[i] = 0.0f;
    if (i < HID) {
        bufA[(size_t)SENT * HID + i] = 0;
        bufB[(size_t)SENT * HID + i] = 0;
    }
}

// ---------------------------------------------------------------- degree ----
__global__ void deg_kernel(const int* __restrict__ dst, int* __restrict__ deg,
                           int n_edges) {
    int t = blockIdx.x * blockDim.x + threadIdx.x;
    int e0 = t * 4;
    if (e0 + 4 <= n_edges) {
        int4 d4 = *(const int4*)(dst + e0);
        atomicAdd(&deg[d4.x], 1);
        atomicAdd(&deg[d4.y], 1);
        atomicAdd(&deg[d4.z], 1);
        atomicAdd(&deg[d4.w], 1);
    } else {
        for (int e = e0; e < n_edges; e++) atomicAdd(&deg[dst[e]], 1);
    }
}

// ------------------------------------------- scan (padded to 8) + dinv ------
__global__ __launch_bounds__(256) void scan_phaseA(const int* __restrict__ deg,
                                                   float* __restrict__ dinv,
                                                   int* __restrict__ blocksum,
                                                   int N) {
    int i = blockIdx.x * 256 + threadIdx.x;
    int d = (i < N) ? deg[i] : 0;
    if (i < N) dinv[i] = rsqrtf((float)d + 1.0f);
    int v = (d + 7) & ~7;  // padded degree
#pragma unroll
    for (int off = 32; off > 0; off >>= 1) v += __shfl_down(v, off, 64);
    __shared__ int s[4];
    if ((threadIdx.x & 63) == 0) s[threadIdx.x >> 6] = v;
    __syncthreads();
    if (threadIdx.x == 0) blocksum[blockIdx.x] = s[0] + s[1] + s[2] + s[3];
}

// Phase B folded in: each block reduces the NB block-sums itself.
__global__ __launch_bounds__(256) void scan_phaseC(const int* __restrict__ deg,
                                                   const int* __restrict__ blocksum,
                                                   int* __restrict__ rowptr,
                                                   int* __restrict__ cursor,
                                                   int N, int NB) {
    int t = threadIdx.x;
    // prefix over blocks < blockIdx.x
    int mine = (t < NB && t < blockIdx.x) ? blocksum[t] : 0;
#pragma unroll
    for (int off = 32; off > 0; off >>= 1) mine += __shfl_down(mine, off, 64);
    __shared__ int ps[4];
    if ((t & 63) == 0) ps[t >> 6] = mine;
    __syncthreads();
    int pref = ps[0] + ps[1] + ps[2] + ps[3];

    __shared__ int s[256];
    int i = blockIdx.x * 256 + t;
    int own = (i < N) ? (deg[i] + 7) & ~7 : 0;
    s[t] = own;
    __syncthreads();
#pragma unroll
    for (int off = 1; off < 256; off <<= 1) {
        int v = (t >= off) ? s[t - off] : 0;
        __syncthreads();
        s[t] += v;
        __syncthreads();
    }
    if (i < N) {
        int r = pref + s[t] - own;
        rowptr[i] = r;
        cursor[i] = r;               // seed: atomics return absolute positions
        if (i == N - 1) rowptr[N] = r + own;
    }
}

// ------------------------------------------------------------------ fill ----
// 8 edges/thread: deeper independent atomic pipeline.
__global__ void csr_fill(const int* __restrict__ src, const int* __restrict__ dst,
                         int* __restrict__ cursor,
                         unsigned short* __restrict__ csr_src, int n_edges) {
    int t = blockIdx.x * blockDim.x + threadIdx.x;
    int e0 = t * 8;
    if (e0 + 8 <= n_edges) {
        int4 da = *(const int4*)(dst + e0);
        int4 db = *(const int4*)(dst + e0 + 4);
        int4 sa = *(const int4*)(src + e0);
        int4 sb = *(const int4*)(src + e0 + 4);
        int p0 = atomicAdd(&cursor[da.x], 1);
        int p1 = atomicAdd(&cursor[da.y], 1);
        int p2 = atomicAdd(&cursor[da.z], 1);
        int p3 = atomicAdd(&cursor[da.w], 1);
        int p4 = atomicAdd(&cursor[db.x], 1);
        int p5 = atomicAdd(&cursor[db.y], 1);
        int p6 = atomicAdd(&cursor[db.z], 1);
        int p7 = atomicAdd(&cursor[db.w], 1);
        csr_src[p0] = (unsigned short)sa.x;
        csr_src[p1] = (unsigned short)sa.y;
        csr_src[p2] = (unsigned short)sa.z;
        csr_src[p3] = (unsigned short)sa.w;
        csr_src[p4] = (unsigned short)sb.x;
        csr_src[p5] = (unsigned short)sb.y;
        csr_src[p6] = (unsigned short)sb.z;
        csr_src[p7] = (unsigned short)sb.w;
    } else {
        for (int e = e0; e < n_edges; e++) {
            int p = atomicAdd(&cursor[dst[e]], 1);
            csr_src[p] = (unsigned short)src[e];
        }
    }
}

// ----------------------------------------------------------- weight prep ----
__global__ void swizzle_W(const float* __restrict__ W0, const float* __restrict__ W1,
                          const float* __restrict__ W2, unsigned short* __restrict__ Wz) {
    const float* W = (blockIdx.x == 0) ? W0 : (blockIdx.x == 1) ? W1 : W2;
    unsigned short* dst = Wz + blockIdx.x * HID * HID;
    for (int e = threadIdx.x; e < HID * HID; e += blockDim.x) {
        int k = e / HID, n = e % HID;
        int nt = n >> 4, kki = k >> 5, quad = (k >> 3) & 3, j = k & 7;
        int lane = (n & 15) | (quad << 4);
        dst[(((nt * 3 + kki) * 64 + lane) << 3) | j] = f32_to_bf16(W[e]);
    }
}

// ----------------------------------------------------- GEMM0 (f32 input) ----
__global__ __launch_bounds__(256) void gemm0_f32(
    const float* __restrict__ X, const unsigned short* __restrict__ Wz,
    const float* __restrict__ dinv, unsigned short* __restrict__ Out, int Mtiles) {
    int wv = threadIdx.x >> 6;
    int lane = threadIdx.x & 63;
    int quad = lane >> 4;
    int mrow = lane & 15;
    int tt = blockIdx.x * 2 + (wv >> 1);
    int half = wv & 1;
    if (tt >= Mtiles) return;

    short8 bfrag[9];
    const short8* Wz8 = (const short8*)Wz;
#pragma unroll
    for (int f = 0; f < 9; f++) bfrag[f] = Wz8[(half * 9 + f) * 64 + lane];

    int m0 = tt * 16;
    const float* arow = X + (size_t)(m0 + mrow) * HID + quad * 8;
    short8 a[3];
#pragma unroll
    for (int kb = 0; kb < 3; kb++) {
        float4 u = *(const float4*)(arow + kb * 32);
        float4 v = *(const float4*)(arow + kb * 32 + 4);
        short8 t;
        t[0] = (short)f32_to_bf16(u.x); t[1] = (short)f32_to_bf16(u.y);
        t[2] = (short)f32_to_bf16(u.z); t[3] = (short)f32_to_bf16(u.w);
        t[4] = (short)f32_to_bf16(v.x); t[5] = (short)f32_to_bf16(v.y);
        t[6] = (short)f32_to_bf16(v.z); t[7] = (short)f32_to_bf16(v.w);
        a[kb] = t;
    }
    float dscale[4];
#pragma unroll
    for (int r = 0; r < 4; r++) dscale[r] = dinv[m0 + quad * 4 + r];
    unsigned short* orow = Out + (size_t)m0 * HID;
#pragma unroll
    for (int ntl = 0; ntl < 3; ntl++) {
        int nt = half * 3 + ntl;
        floatx4 c = {0.0f, 0.0f, 0.0f, 0.0f};
        c = __builtin_amdgcn_mfma_f32_16x16x32_bf16(a[0], bfrag[ntl * 3 + 0], c, 0, 0, 0);
        c = __builtin_amdgcn_mfma_f32_16x16x32_bf16(a[1], bfrag[ntl * 3 + 1], c, 0, 0, 0);
        c = __builtin_amdgcn_mfma_f32_16x16x32_bf16(a[2], bfrag[ntl * 3 + 2], c, 0, 0, 0);
#pragma unroll
        for (int r = 0; r < 4; r++)
            orow[(size_t)(quad * 4 + r) * HID + nt * 16 + mrow] =
                f32_to_bf16(c[r] * dscale[r]);
    }
}

// ------------------------------------------------ fused gather + GEMM -------
// Block = 128 (2 waves, 1 tile): finer scheduling; 2-wave barrier only.
__global__ __launch_bounds__(128) void fused_gather_gemm(
    const unsigned short* __restrict__ h, const int* __restrict__ rowptr,
    const unsigned short* __restrict__ csr, const float* __restrict__ dinv,
    const float* __restrict__ bias, const unsigned short* __restrict__ Wz,
    unsigned short* __restrict__ Out, int Mtiles) {
    __shared__ unsigned short tile[16][104];  // stride 104
    int half = threadIdx.x >> 6;
    int lane = threadIdx.x & 63;
    int quad = lane >> 4;
    int mrow = lane & 15;
    int tt = blockIdx.x;
    int fi = (lane < 48) ? lane * 2 : 94;

    {
        float b0 = bias[fi], b1 = bias[fi + 1];
        int n0 = tt * 16;
        for (int jj = 0; jj < 8; jj += 2) {
            int j0 = half * 8 + jj;
            int na = n0 + j0;
            int nb = na + 1;
            int ia = rowptr[na];
            int ea = rowptr[na + 1];
            int ib = ea;               // rows contiguous
            int eb = rowptr[nb + 1];
            float da = dinv[na], db = dinv[nb];
            ushort2 ha = *(const ushort2*)(h + (size_t)na * HID + fi);
            ushort2 hb = *(const ushort2*)(h + (size_t)nb * HID + fi);
            float a00 = bf16_to_f32(ha.x), a01 = bf16_to_f32(ha.y);
            float a10 = bf16_to_f32(hb.x), a11 = bf16_to_f32(hb.y);
            gather2(h, csr, ia, ea, ib, eb, fi, a00, a01, a10, a11);
            a00 = fmaxf(a00 * da + b0, 0.0f);
            a01 = fmaxf(a01 * da + b1, 0.0f);
            a10 = fmaxf(a10 * db + b0, 0.0f);
            a11 = fmaxf(a11 * db + b1, 0.0f);
            if (lane < 48) {
                tile[j0][fi] = f32_to_bf16(a00);
                tile[j0][fi + 1] = f32_to_bf16(a01);
                tile[j0 + 1][fi] = f32_to_bf16(a10);
                tile[j0 + 1][fi + 1] = f32_to_bf16(a11);
            }
        }
    }
    __syncthreads();

    short8 bfrag[9];
    const short8* Wz8 = (const short8*)Wz;
#pragma unroll
    for (int f = 0; f < 9; f++) bfrag[f] = Wz8[(half * 9 + f) * 64 + lane];

    const unsigned short* tp = &tile[0][0];
    short8 a[3];
#pragma unroll
    for (int kb = 0; kb < 3; kb++)
        a[kb] = *(const short8*)(tp + mrow * 104 + quad * 8 + kb * 32);
    int n0 = tt * 16;
    float dscale[4];
#pragma unroll
    for (int r = 0; r < 4; r++) dscale[r] = dinv[n0 + quad * 4 + r];
    unsigned short* orow = Out + (size_t)n0 * HID;
#pragma unroll
    for (int ntl = 0; ntl < 3; ntl++) {
        int nt = half * 3 + ntl;
        floatx4 c = {0.0f, 0.0f, 0.0f, 0.0f};
        c = __builtin_amdgcn_mfma_f32_16x16x32_bf16(a[0], bfrag[ntl * 3 + 0], c, 0, 0, 0);
        c = __builtin_amdgcn_mfma_f32_16x16x32_bf16(a[1], bfrag[ntl * 3 + 1], c, 0, 0, 0);
        c = __builtin_amdgcn_mfma_f32_16x16x32_bf16(a[2], bfrag[ntl * 3 + 2], c, 0, 0, 0);
#pragma unroll
        for (int r = 0; r < 4; r++)
            orow[(size_t)(quad * 4 + r) * HID + nt * 16 + mrow] =
                f32_to_bf16(c[r] * dscale[r]);
    }
}

// ------------------------------------------------- fused gather + pool ------
// Wave per 4 nodes (2 concurrent pairs); in-order run-length pool.
__global__ __launch_bounds__(256) void gather_pool(
    const unsigned short* __restrict__ h, const int* __restrict__ rowptr,
    const unsigned short* __restrict__ csr, const float* __restrict__ dinv,
    const float* __restrict__ bias, const int* __restrict__ batch,
    float* __restrict__ psum, float* __restrict__ pcnt, int Ntiles4) {
    int wv = threadIdx.x >> 6;
    int lane = threadIdx.x & 63;
    int tt = blockIdx.x * 4 + wv;
    if (tt >= Ntiles4) return;
    int fi = (lane < 48) ? lane * 2 : 94;
    float b0 = bias[fi], b1 = bias[fi + 1];

    int n0 = tt * 4;
    int g_cur = batch[n0];
    float s0 = 0.0f, s1 = 0.0f;
    int cnt = 0;
    for (int jj = 0; jj < 4; jj += 2) {
        int na = n0 + jj;
        int nb = na + 1;
        int ia = rowptr[na];
        int ea = rowptr[na + 1];
        int ib = ea;
        int eb = rowptr[nb + 1];
        float da = dinv[na], db = dinv[nb];
        ushort2 ha = *(const ushort2*)(h + (size_t)na * HID + fi);
        ushort2 hb = *(const ushort2*)(h + (size_t)nb * HID + fi);
        float a00 = bf16_to_f32(ha.x), a01 = bf16_to_f32(ha.y);
        float a10 = bf16_to_f32(hb.x), a11 = bf16_to_f32(hb.y);
        gather2(h, csr, ia, ea, ib, eb, fi, a00, a01, a10, a11);
        a00 = a00 * da + b0;  // last layer: no ReLU
        a01 = a01 * da + b1;
        a10 = a10 * db + b0;
        a11 = a11 * db + b1;
        int ga = batch[na];
        if (ga != g_cur) {
            if (lane < 48) {
                atomicAdd(&psum[g_cur * HID + fi], s0);
                atomicAdd(&psum[g_cur * HID + fi + 1], s1);
            }
            if (lane == 0) atomicAdd(&pcnt[g_cur], (float)cnt);
            s0 = 0.0f; s1 = 0.0f; cnt = 0;
            g_cur = ga;
        }
        s0 += a00; s1 += a01; cnt++;
        int gb = batch[nb];
        if (gb != g_cur) {
            if (lane < 48) {
                atomicAdd(&psum[g_cur * HID + fi], s0);
                atomicAdd(&psum[g_cur * HID + fi + 1], s1);
            }
            if (lane == 0) atomicAdd(&pcnt[g_cur], (float)cnt);
            s0 = 0.0f; s1 = 0.0f; cnt = 0;
            g_cur = gb;
        }
        s0 += a10; s1 += a11; cnt++;
    }
    if (lane < 48) {
        atomicAdd(&psum[g_cur * HID + fi], s0);
        atomicAdd(&psum[g_cur * HID + fi + 1], s1);
    }
    if (lane == 0) atomicAdd(&pcnt[g_cur], (float)cnt);
}

// ---------------------------------------------------------------- head ------
__global__ __launch_bounds__(640) void final_kernel(
    const float* __restrict__ sums, const float* __restrict__ cnts,
    const float* __restrict__ Wlin, const float* __restrict__ blin,
    float* __restrict__ out) {
    int t = threadIdx.x;
    if (t >= NGRAPHS * 10) return;
    int g = t / 10;
    int c = t % 10;
    float denom = fmaxf(cnts[g], 1.0f);
    float acc = blin[c];
#pragma unroll
    for (int f = 0; f < HID; f++)
        acc += (sums[g * HID + f] / denom) * Wlin[f * 10 + c];
    out[t] = acc;
}

// ---------------------------------------------------------------- launch ----
extern "C" void kernel_launch(void* const* d_in, const int* in_sizes, int n_in,
                              void* d_out, int out_size, void* d_ws,
                              size_t ws_size, hipStream_t stream) {
    const float* x = (const float*)d_in[0];
    const int* edge = (const int*)d_in[1];
    const int* batch = (const int*)d_in[2];
    const float* W[3] = {(const float*)d_in[3], (const float*)d_in[5],
                         (const float*)d_in[7]};
    const float* B[3] = {(const float*)d_in[4], (const float*)d_in[6],
                         (const float*)d_in[8]};
    const float* Wlin = (const float*)d_in[9];
    const float* blin = (const float*)d_in[10];
    float* out = (float*)d_out;

    int N = in_sizes[0] / HID;  // 50000
    int E = in_sizes[1] / 2;    // 800000
    const int* src = edge;
    const int* dst = edge + E;
    int NB = (N + 255) / 256;   // 196

    char* ws = (char*)d_ws;
    size_t off = 0;
    auto alloc = [&](size_t bytes) {
        void* p = ws + off;
        off += (bytes + 255) & ~(size_t)255;
        return p;
    };
    int* deg = (int*)alloc((size_t)N * 4);
    float* dinv = (float*)alloc((size_t)N * 4);
    int* rowptr = (int*)alloc(((size_t)N + 1) * 4);
    int* cursor = (int*)alloc((size_t)N * 4);
    int* blocksum = (int*)alloc((size_t)NB * 4);
    size_t csr_cap = (size_t)E + 8 * (size_t)N;
    unsigned short* csr_src = (unsigned short*)alloc(csr_cap * 2 + 64);
    unsigned short* Wz = (unsigned short*)alloc(3 * HID * HID * 2);
    unsigned short* bufA = (unsigned short*)alloc((size_t)NROWS * HID * 2);
    unsigned short* bufB = (unsigned short*)alloc((size_t)NROWS * HID * 2);
    float* psum = (float*)alloc((NGRAPHS * HID + NGRAPHS) * 4);
    float* pcnt = psum + NGRAPHS * HID;

    // --- CSR build + weight prep ---
    hipMemsetAsync(csr_src, 0xC3, csr_cap * 2, stream);  // pads -> sentinel row
    init_kernel<<<NB, 256, 0, stream>>>(deg, psum, bufA, bufB, N);
    deg_kernel<<<(E / 4 + 255) / 256, 256, 0, stream>>>(dst, deg, E);
    scan_phaseA<<<NB, 256, 0, stream>>>(deg, dinv, blocksum, N);
    scan_phaseC<<<NB, 256, 0, stream>>>(deg, blocksum, rowptr, cursor, N, NB);
    csr_fill<<<(E / 8 + 255) / 256, 256, 0, stream>>>(src, dst, cursor, csr_src, E);
    swizzle_W<<<3, 256, 0, stream>>>(W[0], W[1], W[2], Wz);

    int Mtiles = (N + 15) / 16;           // 3125 (exact: N = 50000)
    int grid2 = (Mtiles + 1) / 2;         // 1563 (gemm0: 2 tiles/block)
    int Ntiles4 = (N + 3) / 4;            // 12500
    int gridp = (Ntiles4 + 3) / 4;        // 3125

    gemm0_f32<<<grid2, 256, 0, stream>>>(x, Wz, dinv, bufA, Mtiles);
    fused_gather_gemm<<<Mtiles, 128, 0, stream>>>(
        bufA, rowptr, csr_src, dinv, B[0], Wz + 1 * HID * HID, bufB, Mtiles);
    fused_gather_gemm<<<Mtiles, 128, 0, stream>>>(
        bufB, rowptr, csr_src, dinv, B[1], Wz + 2 * HID * HID, bufA, Mtiles);
    gather_pool<<<gridp, 256, 0, stream>>>(bufA, rowptr, csr_src, dinv, B[2],
                                           batch, psum, pcnt, Ntiles4);
    final_kernel<<<1, 640, 0, stream>>>(psum, pcnt, Wlin, blin, out);
}

// Round 12
// 306.970 us; speedup vs baseline: 1.1677x; 1.1677x over previous
//
#include <hip/hip_runtime.h>
#include <hip/hip_bf16.h>

#define HID 96
#define NGRAPHS 64
#define SENT 0xC3C3u   // 50115: sentinel row (zeroed) for CSR padding
#define NROWS 50116    // N + sentinel row

typedef __attribute__((ext_vector_type(8))) short short8;
typedef __attribute__((ext_vector_type(4))) float floatx4;
typedef __attribute__((ext_vector_type(8))) unsigned short ushort8v;

__device__ __forceinline__ float bf16_to_f32(unsigned short u) {
    unsigned int v = ((unsigned int)u) << 16;
    return __builtin_bit_cast(float, v);
}
__device__ __forceinline__ unsigned short f32_to_bf16(float f) {
    unsigned int u = __builtin_bit_cast(unsigned int, f);
    u += 0x7fff + ((u >> 16) & 1);  // RNE
    return (unsigned short)(u >> 16);
}

// One 8-edge batch of one row.
__device__ __forceinline__ void gather_batch(const unsigned short* __restrict__ h,
                                             const unsigned short* __restrict__ csr,
                                             int i, int fi, float& a0, float& a1) {
    ushort8v iv = *(const ushort8v*)(csr + i);
    ushort2 v0 = *(const ushort2*)(h + (size_t)iv[0] * HID + fi);
    ushort2 v1 = *(const ushort2*)(h + (size_t)iv[1] * HID + fi);
    ushort2 v2 = *(const ushort2*)(h + (size_t)iv[2] * HID + fi);
    ushort2 v3 = *(const ushort2*)(h + (size_t)iv[3] * HID + fi);
    ushort2 v4 = *(const ushort2*)(h + (size_t)iv[4] * HID + fi);
    ushort2 v5 = *(const ushort2*)(h + (size_t)iv[5] * HID + fi);
    ushort2 v6 = *(const ushort2*)(h + (size_t)iv[6] * HID + fi);
    ushort2 v7 = *(const ushort2*)(h + (size_t)iv[7] * HID + fi);
    a0 += bf16_to_f32(v0.x) + bf16_to_f32(v1.x) + bf16_to_f32(v2.x) +
          bf16_to_f32(v3.x) + bf16_to_f32(v4.x) + bf16_to_f32(v5.x) +
          bf16_to_f32(v6.x) + bf16_to_f32(v7.x);
    a1 += bf16_to_f32(v0.y) + bf16_to_f32(v1.y) + bf16_to_f32(v2.y) +
          bf16_to_f32(v3.y) + bf16_to_f32(v4.y) + bf16_to_f32(v5.y) +
          bf16_to_f32(v6.y) + bf16_to_f32(v7.y);
}

// Two rows gathered concurrently; 16+ loads in flight per wave.
__device__ __forceinline__ void gather2(const unsigned short* __restrict__ h,
                                        const unsigned short* __restrict__ csr,
                                        int i0, int e0, int i1, int e1, int fi,
                                        float& a00, float& a01, float& a10,
                                        float& a11) {
    while (i0 < e0 && i1 < e1) {
        ushort8v ca = *(const ushort8v*)(csr + i0);
        ushort8v cb = *(const ushort8v*)(csr + i1);
        i0 += 8;
        i1 += 8;
        ushort2 u0 = *(const ushort2*)(h + (size_t)ca[0] * HID + fi);
        ushort2 u1 = *(const ushort2*)(h + (size_t)ca[1] * HID + fi);
        ushort2 u2 = *(const ushort2*)(h + (size_t)ca[2] * HID + fi);
        ushort2 u3 = *(const ushort2*)(h + (size_t)ca[3] * HID + fi);
        ushort2 u4 = *(const ushort2*)(h + (size_t)ca[4] * HID + fi);
        ushort2 u5 = *(const ushort2*)(h + (size_t)ca[5] * HID + fi);
        ushort2 u6 = *(const ushort2*)(h + (size_t)ca[6] * HID + fi);
        ushort2 u7 = *(const ushort2*)(h + (size_t)ca[7] * HID + fi);
        ushort2 w0 = *(const ushort2*)(h + (size_t)cb[0] * HID + fi);
        ushort2 w1 = *(const ushort2*)(h + (size_t)cb[1] * HID + fi);
        ushort2 w2 = *(const ushort2*)(h + (size_t)cb[2] * HID + fi);
        ushort2 w3 = *(const ushort2*)(h + (size_t)cb[3] * HID + fi);
        ushort2 w4 = *(const ushort2*)(h + (size_t)cb[4] * HID + fi);
        ushort2 w5 = *(const ushort2*)(h + (size_t)cb[5] * HID + fi);
        ushort2 w6 = *(const ushort2*)(h + (size_t)cb[6] * HID + fi);
        ushort2 w7 = *(const ushort2*)(h + (size_t)cb[7] * HID + fi);
        a00 += bf16_to_f32(u0.x) + bf16_to_f32(u1.x) + bf16_to_f32(u2.x) +
               bf16_to_f32(u3.x) + bf16_to_f32(u4.x) + bf16_to_f32(u5.x) +
               bf16_to_f32(u6.x) + bf16_to_f32(u7.x);
        a01 += bf16_to_f32(u0.y) + bf16_to_f32(u1.y) + bf16_to_f32(u2.y) +
               bf16_to_f32(u3.y) + bf16_to_f32(u4.y) + bf16_to_f32(u5.y) +
               bf16_to_f32(u6.y) + bf16_to_f32(u7.y);
        a10 += bf16_to_f32(w0.x) + bf16_to_f32(w1.x) + bf16_to_f32(w2.x) +
               bf16_to_f32(w3.x) + bf16_to_f32(w4.x) + bf16_to_f32(w5.x) +
               bf16_to_f32(w6.x) + bf16_to_f32(w7.x);
        a11 += bf16_to_f32(w0.y) + bf16_to_f32(w1.y) + bf16_to_f32(w2.y) +
               bf16_to_f32(w3.y) + bf16_to_f32(w4.y) + bf16_to_f32(w5.y) +
               bf16_to_f32(w6.y) + bf16_to_f32(w7.y);
    }
    for (; i0 < e0; i0 += 8) gather_batch(h, csr, i0, fi, a00, a01);
    for (; i1 < e1; i1 += 8) gather_batch(h, csr, i1, fi, a10, a11);
}

// ------------------------------------------------------------------ init ----
// Replaces: memset(deg), memset(psum), zero_sentinel.
__global__ __launch_bounds__(256) void init_kernel(
    int* __restrict__ deg, float* __restrict__ psum,
    unsigned short* __restrict__ bufA, unsigned short* __restrict__ bufB, int N) {
    int i = blockIdx.x * 256 + threadIdx.x;
    if (i < N) deg[i] = 0;
    if (i < NGRAPHS * HID + NGRAPHS) psum[i] = 0.0f;
    if (i < HID) {
        bufA[(size_t)SENT * HID + i] = 0;
        bufB[(size_t)SENT * HID + i] = 0;
    }
}

// ---------------------------------------------------------------- degree ----
__global__ void deg_kernel(const int* __restrict__ dst, int* __restrict__ deg,
                           int n_edges) {
    int t = blockIdx.x * blockDim.x + threadIdx.x;
    int e0 = t * 4;
    if (e0 + 4 <= n_edges) {
        int4 d4 = *(const int4*)(dst + e0);
        atomicAdd(&deg[d4.x], 1);
        atomicAdd(&deg[d4.y], 1);
        atomicAdd(&deg[d4.z], 1);
        atomicAdd(&deg[d4.w], 1);
    } else {
        for (int e = e0; e < n_edges; e++) atomicAdd(&deg[dst[e]], 1);
    }
}

// ------------------------------------------- scan (padded to 8) + dinv ------
__global__ __launch_bounds__(256) void scan_phaseA(const int* __restrict__ deg,
                                                   float* __restrict__ dinv,
                                                   int* __restrict__ blocksum,
                                                   int N) {
    int i = blockIdx.x * 256 + threadIdx.x;
    int d = (i < N) ? deg[i] : 0;
    if (i < N) dinv[i] = rsqrtf((float)d + 1.0f);
    int v = (d + 7) & ~7;  // padded degree
#pragma unroll
    for (int off = 32; off > 0; off >>= 1) v += __shfl_down(v, off, 64);
    __shared__ int s[4];
    if ((threadIdx.x & 63) == 0) s[threadIdx.x >> 6] = v;
    __syncthreads();
    if (threadIdx.x == 0) blocksum[blockIdx.x] = s[0] + s[1] + s[2] + s[3];
}

// Phase B folded in: each block reduces the NB block-sums itself.
__global__ __launch_bounds__(256) void scan_phaseC(const int* __restrict__ deg,
                                                   const int* __restrict__ blocksum,
                                                   int* __restrict__ rowptr,
                                                   int* __restrict__ cursor,
                                                   int N, int NB) {
    int t = threadIdx.x;
    int mine = (t < NB && t < blockIdx.x) ? blocksum[t] : 0;
#pragma unroll
    for (int off = 32; off > 0; off >>= 1) mine += __shfl_down(mine, off, 64);
    __shared__ int ps[4];
    if ((t & 63) == 0) ps[t >> 6] = mine;
    __syncthreads();
    int pref = ps[0] + ps[1] + ps[2] + ps[3];

    __shared__ int s[256];
    int i = blockIdx.x * 256 + t;
    int own = (i < N) ? (deg[i] + 7) & ~7 : 0;
    s[t] = own;
    __syncthreads();
#pragma unroll
    for (int off = 1; off < 256; off <<= 1) {
        int v = (t >= off) ? s[t - off] : 0;
        __syncthreads();
        s[t] += v;
        __syncthreads();
    }
    if (i < N) {
        int r = pref + s[t] - own;
        rowptr[i] = r;
        cursor[i] = r;               // seed: atomics return absolute positions
        if (i == N - 1) rowptr[N] = r + own;
    }
}

// ------------------------------------------------------------------ fill ----
// 8 edges/thread: deep independent atomic pipeline.
__global__ void csr_fill(const int* __restrict__ src, const int* __restrict__ dst,
                         int* __restrict__ cursor,
                         unsigned short* __restrict__ csr_src, int n_edges) {
    int t = blockIdx.x * blockDim.x + threadIdx.x;
    int e0 = t * 8;
    if (e0 + 8 <= n_edges) {
        int4 da = *(const int4*)(dst + e0);
        int4 db = *(const int4*)(dst + e0 + 4);
        int4 sa = *(const int4*)(src + e0);
        int4 sb = *(const int4*)(src + e0 + 4);
        int p0 = atomicAdd(&cursor[da.x], 1);
        int p1 = atomicAdd(&cursor[da.y], 1);
        int p2 = atomicAdd(&cursor[da.z], 1);
        int p3 = atomicAdd(&cursor[da.w], 1);
        int p4 = atomicAdd(&cursor[db.x], 1);
        int p5 = atomicAdd(&cursor[db.y], 1);
        int p6 = atomicAdd(&cursor[db.z], 1);
        int p7 = atomicAdd(&cursor[db.w], 1);
        csr_src[p0] = (unsigned short)sa.x;
        csr_src[p1] = (unsigned short)sa.y;
        csr_src[p2] = (unsigned short)sa.z;
        csr_src[p3] = (unsigned short)sa.w;
        csr_src[p4] = (unsigned short)sb.x;
        csr_src[p5] = (unsigned short)sb.y;
        csr_src[p6] = (unsigned short)sb.z;
        csr_src[p7] = (unsigned short)sb.w;
    } else {
        for (int e = e0; e < n_edges; e++) {
            int p = atomicAdd(&cursor[dst[e]], 1);
            csr_src[p] = (unsigned short)src[e];
        }
    }
}

// ----------------------------------------------------------- weight prep ----
__global__ void swizzle_W(const float* __restrict__ W0, const float* __restrict__ W1,
                          const float* __restrict__ W2, unsigned short* __restrict__ Wz) {
    const float* W = (blockIdx.x == 0) ? W0 : (blockIdx.x == 1) ? W1 : W2;
    unsigned short* dst = Wz + blockIdx.x * HID * HID;
    for (int e = threadIdx.x; e < HID * HID; e += blockDim.x) {
        int k = e / HID, n = e % HID;
        int nt = n >> 4, kki = k >> 5, quad = (k >> 3) & 3, j = k & 7;
        int lane = (n & 15) | (quad << 4);
        dst[(((nt * 3 + kki) * 64 + lane) << 3) | j] = f32_to_bf16(W[e]);
    }
}

// ----------------------------------------------------- GEMM0 (f32 input) ----
__global__ __launch_bounds__(256) void gemm0_f32(
    const float* __restrict__ X, const unsigned short* __restrict__ Wz,
    const float* __restrict__ dinv, unsigned short* __restrict__ Out, int Mtiles) {
    int wv = threadIdx.x >> 6;
    int lane = threadIdx.x & 63;
    int quad = lane >> 4;
    int mrow = lane & 15;
    int tt = blockIdx.x * 2 + (wv >> 1);
    int half = wv & 1;
    if (tt >= Mtiles) return;

    short8 bfrag[9];
    const short8* Wz8 = (const short8*)Wz;
#pragma unroll
    for (int f = 0; f < 9; f++) bfrag[f] = Wz8[(half * 9 + f) * 64 + lane];

    int m0 = tt * 16;
    const float* arow = X + (size_t)(m0 + mrow) * HID + quad * 8;
    short8 a[3];
#pragma unroll
    for (int kb = 0; kb < 3; kb++) {
        float4 u = *(const float4*)(arow + kb * 32);
        float4 v = *(const float4*)(arow + kb * 32 + 4);
        short8 t;
        t[0] = (short)f32_to_bf16(u.x); t[1] = (short)f32_to_bf16(u.y);
        t[2] = (short)f32_to_bf16(u.z); t[3] = (short)f32_to_bf16(u.w);
        t[4] = (short)f32_to_bf16(v.x); t[5] = (short)f32_to_bf16(v.y);
        t[6] = (short)f32_to_bf16(v.z); t[7] = (short)f32_to_bf16(v.w);
        a[kb] = t;
    }
    float dscale[4];
#pragma unroll
    for (int r = 0; r < 4; r++) dscale[r] = dinv[m0 + quad * 4 + r];
    unsigned short* orow = Out + (size_t)m0 * HID;
#pragma unroll
    for (int ntl = 0; ntl < 3; ntl++) {
        int nt = half * 3 + ntl;
        floatx4 c = {0.0f, 0.0f, 0.0f, 0.0f};
        c = __builtin_amdgcn_mfma_f32_16x16x32_bf16(a[0], bfrag[ntl * 3 + 0], c, 0, 0, 0);
        c = __builtin_amdgcn_mfma_f32_16x16x32_bf16(a[1], bfrag[ntl * 3 + 1], c, 0, 0, 0);
        c = __builtin_amdgcn_mfma_f32_16x16x32_bf16(a[2], bfrag[ntl * 3 + 2], c, 0, 0, 0);
#pragma unroll
        for (int r = 0; r < 4; r++)
            orow[(size_t)(quad * 4 + r) * HID + nt * 16 + mrow] =
                f32_to_bf16(c[r] * dscale[r]);
    }
}

// ------------------------------------------------ fused gather + GEMM -------
// 2 waves per 16-row tile; each gathers 8 rows (as 4 concurrent pairs) into
// the shared LDS tile, barrier, then MFMAs vs 3 of the 6 n-tiles.
__global__ __launch_bounds__(256) void fused_gather_gemm(
    const unsigned short* __restrict__ h, const int* __restrict__ rowptr,
    const unsigned short* __restrict__ csr, const float* __restrict__ dinv,
    const float* __restrict__ bias, const unsigned short* __restrict__ Wz,
    unsigned short* __restrict__ Out, int Mtiles) {
    __shared__ unsigned short tile[2][16][104];  // stride 104
    int wv = threadIdx.x >> 6;
    int lane = threadIdx.x & 63;
    int quad = lane >> 4;
    int mrow = lane & 15;
    int tsel = wv >> 1;
    int half = wv & 1;
    int tt = blockIdx.x * 2 + tsel;
    bool active = tt < Mtiles;
    int fi = (lane < 48) ? lane * 2 : 94;

    if (active) {
        float b0 = bias[fi], b1 = bias[fi + 1];
        int n0 = tt * 16;
        for (int jj = 0; jj < 8; jj += 2) {
            int j0 = half * 8 + jj;
            int na = n0 + j0;
            int nb = na + 1;
            int ia = rowptr[na];
            int ea = rowptr[na + 1];
            int ib = ea;               // rows contiguous
            int eb = rowptr[nb + 1];
            float da = dinv[na], db = dinv[nb];
            ushort2 ha = *(const ushort2*)(h + (size_t)na * HID + fi);
            ushort2 hb = *(const ushort2*)(h + (size_t)nb * HID + fi);
            float a00 = bf16_to_f32(ha.x), a01 = bf16_to_f32(ha.y);
            float a10 = bf16_to_f32(hb.x), a11 = bf16_to_f32(hb.y);
            gather2(h, csr, ia, ea, ib, eb, fi, a00, a01, a10, a11);
            a00 = fmaxf(a00 * da + b0, 0.0f);
            a01 = fmaxf(a01 * da + b1, 0.0f);
            a10 = fmaxf(a10 * db + b0, 0.0f);
            a11 = fmaxf(a11 * db + b1, 0.0f);
            if (lane < 48) {
                tile[tsel][j0][fi] = f32_to_bf16(a00);
                tile[tsel][j0][fi + 1] = f32_to_bf16(a01);
                tile[tsel][j0 + 1][fi] = f32_to_bf16(a10);
                tile[tsel][j0 + 1][fi + 1] = f32_to_bf16(a11);
            }
        }
    }
    __syncthreads();
    if (!active) return;

    short8 bfrag[9];
    const short8* Wz8 = (const short8*)Wz;
#pragma unroll
    for (int f = 0; f < 9; f++) bfrag[f] = Wz8[(half * 9 + f) * 64 + lane];

    const unsigned short* tp = &tile[tsel][0][0];
    short8 a[3];
#pragma unroll
    for (int kb = 0; kb < 3; kb++)
        a[kb] = *(const short8*)(tp + mrow * 104 + quad * 8 + kb * 32);
    int n0 = tt * 16;
    float dscale[4];
#pragma unroll
    for (int r = 0; r < 4; r++) dscale[r] = dinv[n0 + quad * 4 + r];
    unsigned short* orow = Out + (size_t)n0 * HID;
#pragma unroll
    for (int ntl = 0; ntl < 3; ntl++) {
        int nt = half * 3 + ntl;
        floatx4 c = {0.0f, 0.0f, 0.0f, 0.0f};
        c = __builtin_amdgcn_mfma_f32_16x16x32_bf16(a[0], bfrag[ntl * 3 + 0], c, 0, 0, 0);
        c = __builtin_amdgcn_mfma_f32_16x16x32_bf16(a[1], bfrag[ntl * 3 + 1], c, 0, 0, 0);
        c = __builtin_amdgcn_mfma_f32_16x16x32_bf16(a[2], bfrag[ntl * 3 + 2], c, 0, 0, 0);
#pragma unroll
        for (int r = 0; r < 4; r++)
            orow[(size_t)(quad * 4 + r) * HID + nt * 16 + mrow] =
                f32_to_bf16(c[r] * dscale[r]);
    }
}

// ------------------------------------------------- fused gather + pool ------
// Wave per 8 nodes, gathered as 4 concurrent pairs; in-order run-length pool.
__global__ __launch_bounds__(256) void gather_pool(
    const unsigned short* __restrict__ h, const int* __restrict__ rowptr,
    const unsigned short* __restrict__ csr, const float* __restrict__ dinv,
    const float* __restrict__ bias, const int* __restrict__ batch,
    float* __restrict__ psum, float* __restrict__ pcnt, int Ntiles8) {
    int wv = threadIdx.x >> 6;
    int lane = threadIdx.x & 63;
    int tt = blockIdx.x * 4 + wv;
    if (tt >= Ntiles8) return;
    int fi = (lane < 48) ? lane * 2 : 94;
    float b0 = bias[fi], b1 = bias[fi + 1];

    int n0 = tt * 8;
    int g_cur = batch[n0];
    float s0 = 0.0f, s1 = 0.0f;
    int cnt = 0;
    for (int jj = 0; jj < 8; jj += 2) {
        int na = n0 + jj;
        int nb = na + 1;
        int ia = rowptr[na];
        int ea = rowptr[na + 1];
        int ib = ea;
        int eb = rowptr[nb + 1];
        float da = dinv[na], db = dinv[nb];
        ushort2 ha = *(const ushort2*)(h + (size_t)na * HID + fi);
        ushort2 hb = *(const ushort2*)(h + (size_t)nb * HID + fi);
        float a00 = bf16_to_f32(ha.x), a01 = bf16_to_f32(ha.y);
        float a10 = bf16_to_f32(hb.x), a11 = bf16_to_f32(hb.y);
        gather2(h, csr, ia, ea, ib, eb, fi, a00, a01, a10, a11);
        a00 = a00 * da + b0;  // last layer: no ReLU
        a01 = a01 * da + b1;
        a10 = a10 * db + b0;
        a11 = a11 * db + b1;
        int ga = batch[na];
        if (ga != g_cur) {
            if (lane < 48) {
                atomicAdd(&psum[g_cur * HID + fi], s0);
                atomicAdd(&psum[g_cur * HID + fi + 1], s1);
            }
            if (lane == 0) atomicAdd(&pcnt[g_cur], (float)cnt);
            s0 = 0.0f; s1 = 0.0f; cnt = 0;
            g_cur = ga;
        }
        s0 += a00; s1 += a01; cnt++;
        int gb = batch[nb];
        if (gb != g_cur) {
            if (lane < 48) {
                atomicAdd(&psum[g_cur * HID + fi], s0);
                atomicAdd(&psum[g_cur * HID + fi + 1], s1);
            }
            if (lane == 0) atomicAdd(&pcnt[g_cur], (float)cnt);
            s0 = 0.0f; s1 = 0.0f; cnt = 0;
            g_cur = gb;
        }
        s0 += a10; s1 += a11; cnt++;
    }
    if (lane < 48) {
        atomicAdd(&psum[g_cur * HID + fi], s0);
        atomicAdd(&psum[g_cur * HID + fi + 1], s1);
    }
    if (lane == 0) atomicAdd(&pcnt[g_cur], (float)cnt);
}

// ---------------------------------------------------------------- head ------
__global__ __launch_bounds__(640) void final_kernel(
    const float* __restrict__ sums, const float* __restrict__ cnts,
    const float* __restrict__ Wlin, const float* __restrict__ blin,
    float* __restrict__ out) {
    int t = threadIdx.x;
    if (t >= NGRAPHS * 10) return;
    int g = t / 10;
    int c = t % 10;
    float denom = fmaxf(cnts[g], 1.0f);
    float acc = blin[c];
#pragma unroll
    for (int f = 0; f < HID; f++)
        acc += (sums[g * HID + f] / denom) * Wlin[f * 10 + c];
    out[t] = acc;
}

// ---------------------------------------------------------------- launch ----
extern "C" void kernel_launch(void* const* d_in, const int* in_sizes, int n_in,
                              void* d_out, int out_size, void* d_ws,
                              size_t ws_size, hipStream_t stream) {
    const float* x = (const float*)d_in[0];
    const int* edge = (const int*)d_in[1];
    const int* batch = (const int*)d_in[2];
    const float* W[3] = {(const float*)d_in[3], (const float*)d_in[5],
                         (const float*)d_in[7]};
    const float* B[3] = {(const float*)d_in[4], (const float*)d_in[6],
                         (const float*)d_in[8]};
    const float* Wlin = (const float*)d_in[9];
    const float* blin = (const float*)d_in[10];
    float* out = (float*)d_out;

    int N = in_sizes[0] / HID;  // 50000
    int E = in_sizes[1] / 2;    // 800000
    const int* src = edge;
    const int* dst = edge + E;
    int NB = (N + 255) / 256;   // 196

    char* ws = (char*)d_ws;
    size_t off = 0;
    auto alloc = [&](size_t bytes) {
        void* p = ws + off;
        off += (bytes + 255) & ~(size_t)255;
        return p;
    };
    int* deg = (int*)alloc((size_t)N * 4);
    float* dinv = (float*)alloc((size_t)N * 4);
    int* rowptr = (int*)alloc(((size_t)N + 1) * 4);
    int* cursor = (int*)alloc((size_t)N * 4);
    int* blocksum = (int*)alloc((size_t)NB * 4);
    size_t csr_cap = (size_t)E + 8 * (size_t)N;
    unsigned short* csr_src = (unsigned short*)alloc(csr_cap * 2 + 64);
    unsigned short* Wz = (unsigned short*)alloc(3 * HID * HID * 2);
    unsigned short* bufA = (unsigned short*)alloc((size_t)NROWS * HID * 2);
    unsigned short* bufB = (unsigned short*)alloc((size_t)NROWS * HID * 2);
    float* psum = (float*)alloc((NGRAPHS * HID + NGRAPHS) * 4);
    float* pcnt = psum + NGRAPHS * HID;

    // --- CSR build + weight prep ---
    hipMemsetAsync(csr_src, 0xC3, csr_cap * 2, stream);  // pads -> sentinel row
    init_kernel<<<NB, 256, 0, stream>>>(deg, psum, bufA, bufB, N);
    deg_kernel<<<(E / 4 + 255) / 256, 256, 0, stream>>>(dst, deg, E);
    scan_phaseA<<<NB, 256, 0, stream>>>(deg, dinv, blocksum, N);
    scan_phaseC<<<NB, 256, 0, stream>>>(deg, blocksum, rowptr, cursor, N, NB);
    csr_fill<<<(E / 8 + 255) / 256, 256, 0, stream>>>(src, dst, cursor, csr_src, E);
    swizzle_W<<<3, 256, 0, stream>>>(W[0], W[1], W[2], Wz);

    int Mtiles = (N + 15) / 16;           // 3125
    int grid2 = (Mtiles + 1) / 2;         // 1563 (2 tiles/block)
    int Ntiles8 = (N + 7) / 8;            // 6250
    int gridp = (Ntiles8 + 3) / 4;        // 1563

    gemm0_f32<<<grid2, 256, 0, stream>>>(x, Wz, dinv, bufA, Mtiles);
    fused_gather_gemm<<<grid2, 256, 0, stream>>>(
        bufA, rowptr, csr_src, dinv, B[0], Wz + 1 * HID * HID, bufB, Mtiles);
    fused_gather_gemm<<<grid2, 256, 0, stream>>>(
        bufB, rowptr, csr_src, dinv, B[1], Wz + 2 * HID * HID, bufA, Mtiles);
    gather_pool<<<gridp, 256, 0, stream>>>(bufA, rowptr, csr_src, dinv, B[2],
                                           batch, psum, pcnt, Ntiles8);
    final_kernel<<<1, 640, 0, stream>>>(psum, pcnt, Wlin, blin, out);
}